// Round 1
// baseline (310.173 us; speedup 1.0000x reference)
//
#include <hip/hip_runtime.h>
#include <hip/hip_bf16.h>

#define D 512

typedef __attribute__((ext_vector_type(8))) short bf16x8;
typedef __attribute__((ext_vector_type(4))) float f32x4;

// ---------------- degree histograms ----------------
__global__ void k_hist(const int* __restrict__ src, const int* __restrict__ dst,
                       int* __restrict__ deg_out, int* __restrict__ deg_in, int E) {
    int e = blockIdx.x * 256 + threadIdx.x;
    if (e < E) {
        atomicAdd(&deg_out[src[e]], 1);
        atomicAdd(&deg_in[dst[e]], 1);
    }
}

// ---------------- exclusive scan of deg_in -> row_start (3 kernels) ----------------
__global__ void k_scan1(const int* __restrict__ deg_in, int* __restrict__ row_start,
                        int* __restrict__ partials, int N) {
    __shared__ int sm[1024];
    int tid = threadIdx.x;
    int i = blockIdx.x * 1024 + tid;
    int v = (i < N) ? deg_in[i] : 0;
    sm[tid] = v;
    __syncthreads();
    int acc = v;
    #pragma unroll
    for (int off = 1; off < 1024; off <<= 1) {
        int t = (tid >= off) ? sm[tid - off] : 0;
        __syncthreads();
        acc += t;
        sm[tid] = acc;
        __syncthreads();
    }
    if (i < N) row_start[i] = acc - v;          // exclusive within chunk
    if (tid == 1023) partials[blockIdx.x] = acc; // chunk total
}

__global__ void k_scan2(int* __restrict__ partials, int* __restrict__ row_start,
                        int nb, int N) {
    if (threadIdx.x == 0 && blockIdx.x == 0) {
        int run = 0;
        for (int b = 0; b < nb; b++) { int t = partials[b]; partials[b] = run; run += t; }
        row_start[N] = run; // == E
    }
}

__global__ void k_scan3(int* __restrict__ row_start, const int* __restrict__ partials, int N) {
    int i = blockIdx.x * 256 + threadIdx.x;
    if (i < N) row_start[i] += partials[i >> 10];
}

// ---------------- CSR bucket fill (store src per dst-row) ----------------
__global__ void k_fill(const int* __restrict__ src, const int* __restrict__ dst,
                       const int* __restrict__ row_start, int* __restrict__ cursor,
                       int* __restrict__ csr_src, int E) {
    int e = blockIdx.x * 256 + threadIdx.x;
    if (e < E) {
        int d = dst[e];
        int slot = atomicAdd(&cursor[d], 1);
        csr_src[row_start[d] + slot] = src[e];
    }
}

// ---------------- SpMM: one wave per dst node; write bf16 scaled rows ----------------
__global__ __launch_bounds__(256)
void k_spmm(const float* __restrict__ x, const int* __restrict__ row_start,
            const int* __restrict__ csr_src, const int* __restrict__ deg_out,
            __hip_bfloat16* __restrict__ A, int N) {
    int wid = threadIdx.x >> 6;
    int lane = threadIdx.x & 63;
    int node = blockIdx.x * 4 + wid;
    if (node >= N) return;
    int rs = row_start[node], re = row_start[node + 1];

    float4 acc0 = {0.f, 0.f, 0.f, 0.f};
    float4 acc1 = {0.f, 0.f, 0.f, 0.f};
    const float* xl = x + (size_t)lane * 8;

    for (int j = rs; j < re; j++) {
        int s = csr_src[j];
        float w = rsqrtf((float)max(deg_out[s], 1));
        const float4* p = (const float4*)(xl + (size_t)s * D);
        float4 a = p[0], b = p[1];
        acc0.x += a.x * w; acc0.y += a.y * w; acc0.z += a.z * w; acc0.w += a.w * w;
        acc1.x += b.x * w; acc1.y += b.y * w; acc1.z += b.z * w; acc1.w += b.w * w;
    }
    float rn = rsqrtf((float)max(re - rs, 1));
    union { float4 f4; __hip_bfloat16 h[8]; } o;
    o.h[0] = __float2bfloat16(acc0.x * rn);
    o.h[1] = __float2bfloat16(acc0.y * rn);
    o.h[2] = __float2bfloat16(acc0.z * rn);
    o.h[3] = __float2bfloat16(acc0.w * rn);
    o.h[4] = __float2bfloat16(acc1.x * rn);
    o.h[5] = __float2bfloat16(acc1.y * rn);
    o.h[6] = __float2bfloat16(acc1.z * rn);
    o.h[7] = __float2bfloat16(acc1.w * rn);
    *(float4*)(A + (size_t)node * D + lane * 8) = o.f4;
}

// ---------------- pack W (f32 row-major KxN) into MFMA B-fragment layout bf16 ----------------
// tile id = kt*32 + nt (kt: K-step of 32, nt: 16-col tile). Element for (tile, lane, j):
//   W[kt*32 + (lane>>4)*8 + j][nt*16 + (lane&15)]
__global__ void k_packw(const float* __restrict__ W, __hip_bfloat16* __restrict__ Wp) {
    int tile = blockIdx.x;        // 0..511
    int lane = threadIdx.x;       // 0..63
    int kt = tile >> 5, nt = tile & 31;
    int k0 = kt * 32 + (lane >> 4) * 8;
    int n  = nt * 16 + (lane & 15);
    union { float4 f4; __hip_bfloat16 h[8]; } o;
    #pragma unroll
    for (int j = 0; j < 8; j++)
        o.h[j] = __float2bfloat16(W[(size_t)(k0 + j) * D + n]);
    *(float4*)(Wp + ((size_t)tile * 64 + lane) * 8) = o.f4;
}

// ---------------- fused GEMM (bf16 MFMA) + bias + LayerNorm + exact GELU ----------------
// block = 512 threads = 8 waves: wm = wid>>2 (2 row-groups of 16), wn = wid&3 (4 col-groups of 128)
// per wave: 8 N-tiles of 16x16, K-loop 16 steps of 32.
__global__ __launch_bounds__(512)
void k_gemm(const __hip_bfloat16* __restrict__ A, const __hip_bfloat16* __restrict__ Wp,
            const float* __restrict__ bias, const float* __restrict__ gamma,
            const float* __restrict__ beta, float* __restrict__ out, int M) {
    int tid = threadIdx.x;
    int wid = tid >> 6, lane = tid & 63;
    int wm = wid >> 2, wn = wid & 3;
    int m0 = blockIdx.x * 32 + wm * 16;
    int l4 = lane >> 4;           // 0..3
    int coll = lane & 15;

    int arow = m0 + coll;         // A-fragment row for this lane
    bool rowok = (arow < M);

    f32x4 acc[8];
    #pragma unroll
    for (int t = 0; t < 8; t++) acc[t] = (f32x4){0.f, 0.f, 0.f, 0.f};

    const bf16x8* wpb = (const bf16x8*)Wp;
    for (int kt = 0; kt < 16; kt++) {
        bf16x8 afrag;
        if (rowok) {
            afrag = *(const bf16x8*)(A + (size_t)arow * D + kt * 32 + l4 * 8);
        } else {
            afrag = (bf16x8){0,0,0,0,0,0,0,0};
        }
        const bf16x8* wp = wpb + ((size_t)(kt * 32 + wn * 8) * 64 + lane);
        #pragma unroll
        for (int t = 0; t < 8; t++) {
            bf16x8 bfrag = wp[(size_t)t * 64];
            acc[t] = __builtin_amdgcn_mfma_f32_16x16x32_bf16(afrag, bfrag, acc[t], 0, 0, 0);
        }
    }

    // epilogue: bias add + LN stats. C layout: row = l4*4 + r (within 16-tile), col = coll.
    __shared__ float s_sum[32][4];
    __shared__ float s_sq[32][4];

    #pragma unroll
    for (int r = 0; r < 4; r++) {
        float s = 0.f, q = 0.f;
        #pragma unroll
        for (int t = 0; t < 8; t++) {
            int col = wn * 128 + t * 16 + coll;
            float v = acc[t][r] + bias[col];
            acc[t][r] = v;
            s += v; q += v * v;
        }
        // reduce across the 16 lanes of this l4 group (they share the same 4 rows)
        #pragma unroll
        for (int off = 1; off < 16; off <<= 1) {
            s += __shfl_xor(s, off, 64);
            q += __shfl_xor(q, off, 64);
        }
        if (coll == 0) {
            int rb = wm * 16 + l4 * 4 + r;
            s_sum[rb][wn] = s;
            s_sq[rb][wn] = q;
        }
    }
    __syncthreads();

    #pragma unroll
    for (int r = 0; r < 4; r++) {
        int rb = wm * 16 + l4 * 4 + r;
        int gr = blockIdx.x * 32 + rb;
        if (gr >= M) continue;
        float s = s_sum[rb][0] + s_sum[rb][1] + s_sum[rb][2] + s_sum[rb][3];
        float q = s_sq[rb][0] + s_sq[rb][1] + s_sq[rb][2] + s_sq[rb][3];
        float mean = s * (1.0f / 512.0f);
        float var = q * (1.0f / 512.0f) - mean * mean;
        float rstd = rsqrtf(fmaxf(var, 0.f) + 1e-5f);
        #pragma unroll
        for (int t = 0; t < 8; t++) {
            int col = wn * 128 + t * 16 + coll;
            float y = (acc[t][r] - mean) * rstd * gamma[col] + beta[col];
            float g = 0.5f * y * (1.0f + erff(y * 0.70710678118654752f));
            out[(size_t)gr * D + col] = g;
        }
    }
}

extern "C" void kernel_launch(void* const* d_in, const int* in_sizes, int n_in,
                              void* d_out, int out_size, void* d_ws, size_t ws_size,
                              hipStream_t stream) {
    const float* x     = (const float*)d_in[0];
    const float* W     = (const float*)d_in[1];
    const float* b     = (const float*)d_in[2];
    const float* gamma = (const float*)d_in[3];
    const float* beta  = (const float*)d_in[4];
    const int*   src   = (const int*)d_in[5];
    const int*   dst   = (const int*)d_in[6];
    int N = in_sizes[0] / D;
    int E = in_sizes[5];
    float* out = (float*)d_out;

    // workspace layout
    int* deg_out   = (int*)d_ws;                 // N
    int* deg_in    = deg_out + N;                // N
    int* row_start = deg_in + N;                 // N+1
    int* cursor    = row_start + N + 1;          // N
    int* partials  = cursor + N;                 // <=64
    int* csr_src   = partials + 64;              // E
    uintptr_t p = (uintptr_t)(csr_src + E);
    p = (p + 255) & ~(uintptr_t)255;
    __hip_bfloat16* A = (__hip_bfloat16*)p;      // N*D bf16
    p += (size_t)N * D * sizeof(__hip_bfloat16);
    p = (p + 255) & ~(uintptr_t)255;
    __hip_bfloat16* Wp = (__hip_bfloat16*)p;     // D*D bf16

    hipMemsetAsync(deg_out, 0, (size_t)2 * N * sizeof(int), stream); // deg_out + deg_in
    hipMemsetAsync(cursor, 0, (size_t)N * sizeof(int), stream);

    k_hist<<<(E + 255) / 256, 256, 0, stream>>>(src, dst, deg_out, deg_in, E);
    int nb1 = (N + 1023) / 1024;
    k_scan1<<<nb1, 1024, 0, stream>>>(deg_in, row_start, partials, N);
    k_scan2<<<1, 64, 0, stream>>>(partials, row_start, nb1, N);
    k_scan3<<<(N + 255) / 256, 256, 0, stream>>>(row_start, partials, N);
    k_fill<<<(E + 255) / 256, 256, 0, stream>>>(src, dst, row_start, cursor, csr_src, E);
    k_spmm<<<(N + 3) / 4, 256, 0, stream>>>(x, row_start, csr_src, deg_out, A, N);
    k_packw<<<512, 64, 0, stream>>>(W, Wp);
    k_gemm<<<(N + 31) / 32, 512, 0, stream>>>(A, Wp, b, gamma, beta, out, N);
}

// Round 2
// 275.124 us; speedup vs baseline: 1.1274x; 1.1274x over previous
//
#include <hip/hip_runtime.h>
#include <hip/hip_bf16.h>

#define D 512

typedef __attribute__((ext_vector_type(8))) short bf16x8;
typedef __attribute__((ext_vector_type(4))) float f32x4;

__device__ inline float b2f(short h) {
    union { unsigned u; float f; } c;
    c.u = ((unsigned)(unsigned short)h) << 16;
    return c.f;
}

// ---------------- degree histograms ----------------
__global__ void k_hist(const int* __restrict__ src, const int* __restrict__ dst,
                       int* __restrict__ deg_out, int* __restrict__ deg_in, int E) {
    int e = blockIdx.x * 256 + threadIdx.x;
    if (e < E) {
        atomicAdd(&deg_out[src[e]], 1);
        atomicAdd(&deg_in[dst[e]], 1);
    }
}

// ---------------- pre-scale x by rsqrt(deg_out) -> bf16 xs ----------------
__global__ __launch_bounds__(256)
void k_scale(const float* __restrict__ x, const int* __restrict__ deg_out,
             __hip_bfloat16* __restrict__ xs, int total16) {
    int i = blockIdx.x * 256 + threadIdx.x;   // one thread = 8 elements
    if (i >= total16) return;
    int node = i >> 6;
    float w = rsqrtf((float)max(deg_out[node], 1));
    const float4* p = (const float4*)(x + (size_t)i * 8);
    float4 a = p[0], b = p[1];
    union { float4 f4; __hip_bfloat16 h[8]; } o;
    o.h[0] = __float2bfloat16(a.x * w);
    o.h[1] = __float2bfloat16(a.y * w);
    o.h[2] = __float2bfloat16(a.z * w);
    o.h[3] = __float2bfloat16(a.w * w);
    o.h[4] = __float2bfloat16(b.x * w);
    o.h[5] = __float2bfloat16(b.y * w);
    o.h[6] = __float2bfloat16(b.z * w);
    o.h[7] = __float2bfloat16(b.w * w);
    *(float4*)(xs + (size_t)i * 8) = o.f4;
}

// ---------------- exclusive scan of deg_in -> row_start ----------------
__global__ void k_scan1(const int* __restrict__ deg_in, int* __restrict__ row_start,
                        int* __restrict__ partials, int N) {
    __shared__ int sm[1024];
    int tid = threadIdx.x;
    int i = blockIdx.x * 1024 + tid;
    int v = (i < N) ? deg_in[i] : 0;
    sm[tid] = v;
    __syncthreads();
    int acc = v;
    #pragma unroll
    for (int off = 1; off < 1024; off <<= 1) {
        int t = (tid >= off) ? sm[tid - off] : 0;
        __syncthreads();
        acc += t;
        sm[tid] = acc;
        __syncthreads();
    }
    if (i < N) row_start[i] = acc - v;
    if (tid == 1023) partials[blockIdx.x] = acc;
}

// wave-parallel scan of block partials (nb <= 64)
__global__ void k_scan2w(int* __restrict__ partials, int* __restrict__ row_start,
                         int nb, int N) {
    int lane = threadIdx.x;
    int orig = (lane < nb) ? partials[lane] : 0;
    int v = orig;
    #pragma unroll
    for (int off = 1; off < 64; off <<= 1) {
        int t = __shfl_up(v, off, 64);
        if (lane >= off) v += t;
    }
    if (lane < nb) partials[lane] = v - orig;
    if (lane == 63) row_start[N] = v;
}

// serial fallback (nb > 64; not expected at N=50000)
__global__ void k_scan2s(int* __restrict__ partials, int* __restrict__ row_start,
                         int nb, int N) {
    if (threadIdx.x == 0 && blockIdx.x == 0) {
        int run = 0;
        for (int b = 0; b < nb; b++) { int t = partials[b]; partials[b] = run; run += t; }
        row_start[N] = run;
    }
}

__global__ void k_scan3(int* __restrict__ row_start, const int* __restrict__ partials, int N) {
    int i = blockIdx.x * 256 + threadIdx.x;
    if (i < N) row_start[i] += partials[i >> 10];
}

// ---------------- CSR bucket fill ----------------
__global__ void k_fill(const int* __restrict__ src, const int* __restrict__ dst,
                       const int* __restrict__ row_start, int* __restrict__ cursor,
                       int* __restrict__ csr_src, int E) {
    int e = blockIdx.x * 256 + threadIdx.x;
    if (e < E) {
        int d = dst[e];
        int slot = atomicAdd(&cursor[d], 1);
        csr_src[row_start[d] + slot] = src[e];
    }
}

// ---------------- SpMM over bf16 pre-scaled rows ----------------
__global__ __launch_bounds__(256)
void k_spmm(const __hip_bfloat16* __restrict__ xs, const int* __restrict__ row_start,
            const int* __restrict__ csr_src, __hip_bfloat16* __restrict__ A, int N) {
    int wid = threadIdx.x >> 6;
    int lane = threadIdx.x & 63;
    int node = blockIdx.x * 4 + wid;
    if (node >= N) return;
    int rs = row_start[node], re = row_start[node + 1];

    float acc[8];
    #pragma unroll
    for (int k = 0; k < 8; k++) acc[k] = 0.f;
    const __hip_bfloat16* xl = xs + (size_t)lane * 8;

    int j = rs;
    for (; j + 4 <= re; j += 4) {
        int s0 = csr_src[j], s1 = csr_src[j + 1], s2 = csr_src[j + 2], s3 = csr_src[j + 3];
        bf16x8 v0 = *(const bf16x8*)(xl + (size_t)s0 * D);
        bf16x8 v1 = *(const bf16x8*)(xl + (size_t)s1 * D);
        bf16x8 v2 = *(const bf16x8*)(xl + (size_t)s2 * D);
        bf16x8 v3 = *(const bf16x8*)(xl + (size_t)s3 * D);
        #pragma unroll
        for (int k = 0; k < 8; k++)
            acc[k] += (b2f(v0[k]) + b2f(v1[k])) + (b2f(v2[k]) + b2f(v3[k]));
    }
    for (; j < re; j++) {
        int s = csr_src[j];
        bf16x8 v = *(const bf16x8*)(xl + (size_t)s * D);
        #pragma unroll
        for (int k = 0; k < 8; k++) acc[k] += b2f(v[k]);
    }

    float rn = rsqrtf((float)max(re - rs, 1));
    union { float4 f4; __hip_bfloat16 h[8]; } o;
    #pragma unroll
    for (int k = 0; k < 8; k++) o.h[k] = __float2bfloat16(acc[k] * rn);
    *(float4*)(A + (size_t)node * D + lane * 8) = o.f4;
}

// ---------------- f32 fallback SpMM (if workspace too small for xs) ----------------
__global__ __launch_bounds__(256)
void k_spmm_f32(const float* __restrict__ x, const int* __restrict__ row_start,
                const int* __restrict__ csr_src, const int* __restrict__ deg_out,
                __hip_bfloat16* __restrict__ A, int N) {
    int wid = threadIdx.x >> 6;
    int lane = threadIdx.x & 63;
    int node = blockIdx.x * 4 + wid;
    if (node >= N) return;
    int rs = row_start[node], re = row_start[node + 1];
    float4 acc0 = {0.f, 0.f, 0.f, 0.f};
    float4 acc1 = {0.f, 0.f, 0.f, 0.f};
    const float* xl = x + (size_t)lane * 8;
    for (int j = rs; j < re; j++) {
        int s = csr_src[j];
        float w = rsqrtf((float)max(deg_out[s], 1));
        const float4* p = (const float4*)(xl + (size_t)s * D);
        float4 a = p[0], b = p[1];
        acc0.x += a.x * w; acc0.y += a.y * w; acc0.z += a.z * w; acc0.w += a.w * w;
        acc1.x += b.x * w; acc1.y += b.y * w; acc1.z += b.z * w; acc1.w += b.w * w;
    }
    float rn = rsqrtf((float)max(re - rs, 1));
    union { float4 f4; __hip_bfloat16 h[8]; } o;
    o.h[0] = __float2bfloat16(acc0.x * rn);
    o.h[1] = __float2bfloat16(acc0.y * rn);
    o.h[2] = __float2bfloat16(acc0.z * rn);
    o.h[3] = __float2bfloat16(acc0.w * rn);
    o.h[4] = __float2bfloat16(acc1.x * rn);
    o.h[5] = __float2bfloat16(acc1.y * rn);
    o.h[6] = __float2bfloat16(acc1.z * rn);
    o.h[7] = __float2bfloat16(acc1.w * rn);
    *(float4*)(A + (size_t)node * D + lane * 8) = o.f4;
}

// ---------------- pack W into MFMA B-fragment layout ----------------
__global__ void k_packw(const float* __restrict__ W, __hip_bfloat16* __restrict__ Wp) {
    int tile = blockIdx.x;        // 0..511 : tile = kt*32 + nt
    int lane = threadIdx.x;       // 0..63
    int kt = tile >> 5, nt = tile & 31;
    int k0 = kt * 32 + (lane >> 4) * 8;
    int n  = nt * 16 + (lane & 15);
    union { float4 f4; __hip_bfloat16 h[8]; } o;
    #pragma unroll
    for (int j = 0; j < 8; j++)
        o.h[j] = __float2bfloat16(W[(size_t)(k0 + j) * D + n]);
    *(float4*)(Wp + ((size_t)tile * 64 + lane) * 8) = o.f4;
}

// ---------------- fused GEMM + bias + LayerNorm + exact GELU ----------------
__global__ __launch_bounds__(512)
void k_gemm(const __hip_bfloat16* __restrict__ A, const __hip_bfloat16* __restrict__ Wp,
            const float* __restrict__ bias, const float* __restrict__ gamma,
            const float* __restrict__ beta, float* __restrict__ out, int M) {
    int tid = threadIdx.x;
    int wid = tid >> 6, lane = tid & 63;
    int wm = wid >> 2, wn = wid & 3;
    int m0 = blockIdx.x * 32 + wm * 16;
    int l4 = lane >> 4;
    int coll = lane & 15;

    int arow = m0 + coll;
    bool rowok = (arow < M);

    f32x4 acc[8];
    #pragma unroll
    for (int t = 0; t < 8; t++) acc[t] = (f32x4){0.f, 0.f, 0.f, 0.f};

    const bf16x8* wpb = (const bf16x8*)Wp;
    for (int kt = 0; kt < 16; kt++) {
        bf16x8 afrag;
        if (rowok) {
            afrag = *(const bf16x8*)(A + (size_t)arow * D + kt * 32 + l4 * 8);
        } else {
            afrag = (bf16x8){0,0,0,0,0,0,0,0};
        }
        const bf16x8* wp = wpb + ((size_t)(kt * 32 + wn * 8) * 64 + lane);
        #pragma unroll
        for (int t = 0; t < 8; t++) {
            bf16x8 bfrag = wp[(size_t)t * 64];
            acc[t] = __builtin_amdgcn_mfma_f32_16x16x32_bf16(afrag, bfrag, acc[t], 0, 0, 0);
        }
    }

    __shared__ float s_sum[32][4];
    __shared__ float s_sq[32][4];

    #pragma unroll
    for (int r = 0; r < 4; r++) {
        float s = 0.f, q = 0.f;
        #pragma unroll
        for (int t = 0; t < 8; t++) {
            int col = wn * 128 + t * 16 + coll;
            float v = acc[t][r] + bias[col];
            acc[t][r] = v;
            s += v; q += v * v;
        }
        #pragma unroll
        for (int off = 1; off < 16; off <<= 1) {
            s += __shfl_xor(s, off, 64);
            q += __shfl_xor(q, off, 64);
        }
        if (coll == 0) {
            int rb = wm * 16 + l4 * 4 + r;
            s_sum[rb][wn] = s;
            s_sq[rb][wn] = q;
        }
    }
    __syncthreads();

    #pragma unroll
    for (int r = 0; r < 4; r++) {
        int rb = wm * 16 + l4 * 4 + r;
        int gr = blockIdx.x * 32 + rb;
        if (gr >= M) continue;
        float s = s_sum[rb][0] + s_sum[rb][1] + s_sum[rb][2] + s_sum[rb][3];
        float q = s_sq[rb][0] + s_sq[rb][1] + s_sq[rb][2] + s_sq[rb][3];
        float mean = s * (1.0f / 512.0f);
        float var = q * (1.0f / 512.0f) - mean * mean;
        float rstd = rsqrtf(fmaxf(var, 0.f) + 1e-5f);
        #pragma unroll
        for (int t = 0; t < 8; t++) {
            int col = wn * 128 + t * 16 + coll;
            float y = (acc[t][r] - mean) * rstd * gamma[col] + beta[col];
            float g = 0.5f * y * (1.0f + erff(y * 0.70710678118654752f));
            out[(size_t)gr * D + col] = g;
        }
    }
}

extern "C" void kernel_launch(void* const* d_in, const int* in_sizes, int n_in,
                              void* d_out, int out_size, void* d_ws, size_t ws_size,
                              hipStream_t stream) {
    const float* x     = (const float*)d_in[0];
    const float* W     = (const float*)d_in[1];
    const float* b     = (const float*)d_in[2];
    const float* gamma = (const float*)d_in[3];
    const float* beta  = (const float*)d_in[4];
    const int*   src   = (const int*)d_in[5];
    const int*   dst   = (const int*)d_in[6];
    int N = in_sizes[0] / D;
    int E = in_sizes[5];
    float* out = (float*)d_out;

    // workspace layout: ints | A | Wp | xs (xs last so we can fall back without it)
    int* deg_out   = (int*)d_ws;                 // N
    int* deg_in    = deg_out + N;                // N
    int* row_start = deg_in + N;                 // N+1
    int* cursor    = row_start + N + 1;          // N
    int* partials  = cursor + N;                 // <=64
    int* csr_src   = partials + 64;              // E
    uintptr_t p = (uintptr_t)(csr_src + E);
    p = (p + 255) & ~(uintptr_t)255;
    __hip_bfloat16* A = (__hip_bfloat16*)p;      // N*D bf16
    p += (size_t)N * D * sizeof(__hip_bfloat16);
    p = (p + 255) & ~(uintptr_t)255;
    __hip_bfloat16* Wp = (__hip_bfloat16*)p;     // D*D bf16
    p += (size_t)D * D * sizeof(__hip_bfloat16);
    p = (p + 255) & ~(uintptr_t)255;
    __hip_bfloat16* xs = (__hip_bfloat16*)p;     // N*D bf16
    size_t need_xs = (p - (uintptr_t)d_ws) + (size_t)N * D * sizeof(__hip_bfloat16);
    bool use_bf16_gather = (ws_size >= need_xs);

    hipMemsetAsync(deg_out, 0, (size_t)2 * N * sizeof(int), stream);
    hipMemsetAsync(cursor, 0, (size_t)N * sizeof(int), stream);

    k_hist<<<(E + 255) / 256, 256, 0, stream>>>(src, dst, deg_out, deg_in, E);
    int nb1 = (N + 1023) / 1024;
    k_scan1<<<nb1, 1024, 0, stream>>>(deg_in, row_start, partials, N);
    if (nb1 <= 64)
        k_scan2w<<<1, 64, 0, stream>>>(partials, row_start, nb1, N);
    else
        k_scan2s<<<1, 64, 0, stream>>>(partials, row_start, nb1, N);
    k_scan3<<<(N + 255) / 256, 256, 0, stream>>>(row_start, partials, N);
    k_fill<<<(E + 255) / 256, 256, 0, stream>>>(src, dst, row_start, cursor, csr_src, E);

    if (use_bf16_gather) {
        int total16 = N * 64;   // threads of 8 elements each
        k_scale<<<(total16 + 255) / 256, 256, 0, stream>>>(x, deg_out, xs, total16);
        k_spmm<<<(N + 3) / 4, 256, 0, stream>>>(xs, row_start, csr_src, A, N);
    } else {
        k_spmm_f32<<<(N + 3) / 4, 256, 0, stream>>>(x, row_start, csr_src, deg_out, A, N);
    }
    k_packw<<<512, 64, 0, stream>>>(W, Wp);
    k_gemm<<<(N + 31) / 32, 512, 0, stream>>>(A, Wp, b, gamma, beta, out, N);
}

// Round 3
// 247.096 us; speedup vs baseline: 1.2553x; 1.1134x over previous
//
#include <hip/hip_runtime.h>
#include <hip/hip_bf16.h>

#define D 512

typedef __attribute__((ext_vector_type(8))) short bf16x8;
typedef __attribute__((ext_vector_type(4))) float f32x4;

__device__ inline float b2f(short h) {
    union { unsigned u; float f; } c;
    c.u = ((unsigned)(unsigned short)h) << 16;
    return c.f;
}

__device__ __forceinline__ void stage16(const void* g, void* l) {
    __builtin_amdgcn_global_load_lds((const __attribute__((address_space(1))) void*)g,
                                     (__attribute__((address_space(3))) void*)l, 16, 0, 0);
}

// ---------------- degree histograms ----------------
__global__ void k_hist(const int* __restrict__ src, const int* __restrict__ dst,
                       int* __restrict__ deg_out, int* __restrict__ deg_in, int E) {
    int e = blockIdx.x * 256 + threadIdx.x;
    if (e < E) {
        atomicAdd(&deg_out[src[e]], 1);
        atomicAdd(&deg_in[dst[e]], 1);
    }
}

// ---------------- pre-scale x by rsqrt(deg_out) -> bf16 xs ----------------
__global__ __launch_bounds__(256)
void k_scale(const float* __restrict__ x, const int* __restrict__ deg_out,
             __hip_bfloat16* __restrict__ xs, int total16) {
    int i = blockIdx.x * 256 + threadIdx.x;   // one thread = 8 elements
    if (i >= total16) return;
    int node = i >> 6;
    float w = rsqrtf((float)max(deg_out[node], 1));
    const float4* p = (const float4*)(x + (size_t)i * 8);
    float4 a = p[0], b = p[1];
    union { float4 f4; __hip_bfloat16 h[8]; } o;
    o.h[0] = __float2bfloat16(a.x * w);
    o.h[1] = __float2bfloat16(a.y * w);
    o.h[2] = __float2bfloat16(a.z * w);
    o.h[3] = __float2bfloat16(a.w * w);
    o.h[4] = __float2bfloat16(b.x * w);
    o.h[5] = __float2bfloat16(b.y * w);
    o.h[6] = __float2bfloat16(b.z * w);
    o.h[7] = __float2bfloat16(b.w * w);
    *(float4*)(xs + (size_t)i * 8) = o.f4;
}

// ---------------- exclusive scan of deg_in -> row_start ----------------
__global__ void k_scan1(const int* __restrict__ deg_in, int* __restrict__ row_start,
                        int* __restrict__ partials, int N) {
    __shared__ int sm[1024];
    int tid = threadIdx.x;
    int i = blockIdx.x * 1024 + tid;
    int v = (i < N) ? deg_in[i] : 0;
    sm[tid] = v;
    __syncthreads();
    int acc = v;
    #pragma unroll
    for (int off = 1; off < 1024; off <<= 1) {
        int t = (tid >= off) ? sm[tid - off] : 0;
        __syncthreads();
        acc += t;
        sm[tid] = acc;
        __syncthreads();
    }
    if (i < N) row_start[i] = acc - v;
    if (tid == 1023) partials[blockIdx.x] = acc;
}

__global__ void k_scan2w(int* __restrict__ partials, int* __restrict__ row_start,
                         int nb, int N) {
    int lane = threadIdx.x;
    int orig = (lane < nb) ? partials[lane] : 0;
    int v = orig;
    #pragma unroll
    for (int off = 1; off < 64; off <<= 1) {
        int t = __shfl_up(v, off, 64);
        if (lane >= off) v += t;
    }
    if (lane < nb) partials[lane] = v - orig;
    if (lane == 63) row_start[N] = v;
}

__global__ void k_scan2s(int* __restrict__ partials, int* __restrict__ row_start,
                         int nb, int N) {
    if (threadIdx.x == 0 && blockIdx.x == 0) {
        int run = 0;
        for (int b = 0; b < nb; b++) { int t = partials[b]; partials[b] = run; run += t; }
        row_start[N] = run;
    }
}

__global__ void k_scan3(int* __restrict__ row_start, const int* __restrict__ partials, int N) {
    int i = blockIdx.x * 256 + threadIdx.x;
    if (i < N) row_start[i] += partials[i >> 10];
}

// ---------------- CSR bucket fill ----------------
__global__ void k_fill(const int* __restrict__ src, const int* __restrict__ dst,
                       const int* __restrict__ row_start, int* __restrict__ cursor,
                       int* __restrict__ csr_src, int E) {
    int e = blockIdx.x * 256 + threadIdx.x;
    if (e < E) {
        int d = dst[e];
        int slot = atomicAdd(&cursor[d], 1);
        csr_src[row_start[d] + slot] = src[e];
    }
}

// ---------------- SpMM over bf16 pre-scaled rows ----------------
__global__ __launch_bounds__(256)
void k_spmm(const __hip_bfloat16* __restrict__ xs, const int* __restrict__ row_start,
            const int* __restrict__ csr_src, __hip_bfloat16* __restrict__ A, int N) {
    int wid = threadIdx.x >> 6;
    int lane = threadIdx.x & 63;
    int node = blockIdx.x * 4 + wid;
    if (node >= N) return;
    int rs = row_start[node], re = row_start[node + 1];

    float acc[8];
    #pragma unroll
    for (int k = 0; k < 8; k++) acc[k] = 0.f;
    const __hip_bfloat16* xl = xs + (size_t)lane * 8;

    int j = rs;
    for (; j + 4 <= re; j += 4) {
        int s0 = csr_src[j], s1 = csr_src[j + 1], s2 = csr_src[j + 2], s3 = csr_src[j + 3];
        bf16x8 v0 = *(const bf16x8*)(xl + (size_t)s0 * D);
        bf16x8 v1 = *(const bf16x8*)(xl + (size_t)s1 * D);
        bf16x8 v2 = *(const bf16x8*)(xl + (size_t)s2 * D);
        bf16x8 v3 = *(const bf16x8*)(xl + (size_t)s3 * D);
        #pragma unroll
        for (int k = 0; k < 8; k++)
            acc[k] += (b2f(v0[k]) + b2f(v1[k])) + (b2f(v2[k]) + b2f(v3[k]));
    }
    for (; j < re; j++) {
        int s = csr_src[j];
        bf16x8 v = *(const bf16x8*)(xl + (size_t)s * D);
        #pragma unroll
        for (int k = 0; k < 8; k++) acc[k] += b2f(v[k]);
    }

    float rn = rsqrtf((float)max(re - rs, 1));
    union { float4 f4; __hip_bfloat16 h[8]; } o;
    #pragma unroll
    for (int k = 0; k < 8; k++) o.h[k] = __float2bfloat16(acc[k] * rn);
    *(float4*)(A + (size_t)node * D + lane * 8) = o.f4;
}

// ---------------- f32 fallback SpMM ----------------
__global__ __launch_bounds__(256)
void k_spmm_f32(const float* __restrict__ x, const int* __restrict__ row_start,
                const int* __restrict__ csr_src, const int* __restrict__ deg_out,
                __hip_bfloat16* __restrict__ A, int N) {
    int wid = threadIdx.x >> 6;
    int lane = threadIdx.x & 63;
    int node = blockIdx.x * 4 + wid;
    if (node >= N) return;
    int rs = row_start[node], re = row_start[node + 1];
    float4 acc0 = {0.f, 0.f, 0.f, 0.f};
    float4 acc1 = {0.f, 0.f, 0.f, 0.f};
    const float* xl = x + (size_t)lane * 8;
    for (int j = rs; j < re; j++) {
        int s = csr_src[j];
        float w = rsqrtf((float)max(deg_out[s], 1));
        const float4* p = (const float4*)(xl + (size_t)s * D);
        float4 a = p[0], b = p[1];
        acc0.x += a.x * w; acc0.y += a.y * w; acc0.z += a.z * w; acc0.w += a.w * w;
        acc1.x += b.x * w; acc1.y += b.y * w; acc1.z += b.z * w; acc1.w += b.w * w;
    }
    float rn = rsqrtf((float)max(re - rs, 1));
    union { float4 f4; __hip_bfloat16 h[8]; } o;
    o.h[0] = __float2bfloat16(acc0.x * rn);
    o.h[1] = __float2bfloat16(acc0.y * rn);
    o.h[2] = __float2bfloat16(acc0.z * rn);
    o.h[3] = __float2bfloat16(acc0.w * rn);
    o.h[4] = __float2bfloat16(acc1.x * rn);
    o.h[5] = __float2bfloat16(acc1.y * rn);
    o.h[6] = __float2bfloat16(acc1.z * rn);
    o.h[7] = __float2bfloat16(acc1.w * rn);
    *(float4*)(A + (size_t)node * D + lane * 8) = o.f4;
}

// ---------------- pack W into MFMA B-fragment layout ----------------
// tile = kt*32 + nt; element (tile, lane, j) = W[kt*32 + (lane>>4)*8 + j][nt*16 + (lane&15)]
// => per-kt slice (32 tiles) is a contiguous 32KB block: perfect for global_load_lds.
__global__ void k_packw(const float* __restrict__ W, __hip_bfloat16* __restrict__ Wp) {
    int tile = blockIdx.x;        // 0..511
    int lane = threadIdx.x;       // 0..63
    int kt = tile >> 5, nt = tile & 31;
    int k0 = kt * 32 + (lane >> 4) * 8;
    int n  = nt * 16 + (lane & 15);
    union { float4 f4; __hip_bfloat16 h[8]; } o;
    #pragma unroll
    for (int j = 0; j < 8; j++)
        o.h[j] = __float2bfloat16(W[(size_t)(k0 + j) * D + n]);
    *(float4*)(Wp + ((size_t)tile * 64 + lane) * 8) = o.f4;
}

// ---------------- fused GEMM + bias + LayerNorm + tanh-GELU ----------------
// 512 thr = 8 waves (wm 0..1 x wn 0..3); block = 64 rows x 512 cols;
// per wave 2 M-frags (rows wm*16 and wm*16+32), 8 N-tiles, K-loop 16 x 32.
// Wp K-slices staged to LDS (double-buffered 2x32KB) via global_load_lds.
__global__ __launch_bounds__(512, 4)
void k_gemm(const __hip_bfloat16* __restrict__ A, const __hip_bfloat16* __restrict__ Wp,
            const float* __restrict__ bias, const float* __restrict__ gamma,
            const float* __restrict__ beta, float* __restrict__ out, int M) {
    __shared__ __align__(16) char smem[65536];
    __shared__ float s_sum[64][4];
    __shared__ float s_sq[64][4];

    int tid = threadIdx.x;
    int wid = tid >> 6, lane = tid & 63;
    int wm = wid >> 1 & 0 ? 0 : (wid >> 2);  // wm = wid>>2
    wm = wid >> 2;
    int wn = wid & 3;
    int l4 = lane >> 4, coll = lane & 15;
    int bm0 = blockIdx.x * 64;

    int arow0 = bm0 + wm * 16 + coll;
    int arow1 = arow0 + 32;
    if (arow0 > M - 1) arow0 = M - 1;   // clamp: C row depends only on A row; OOB never stored
    if (arow1 > M - 1) arow1 = M - 1;
    const bf16x8* a0p = (const bf16x8*)(A + (size_t)arow0 * D + l4 * 8);
    const bf16x8* a1p = (const bf16x8*)(A + (size_t)arow1 * D + l4 * 8);

    // staging: chunk c = wid*4 + r covers bytes [c*1024, c*1024+1024) of the 32KB slice
    int c0 = wid * 4;
    const __hip_bfloat16* gbase = Wp + (size_t)c0 * 512 + lane * 8;  // +kt*16384, +r*512
    char* lds_c0 = smem + c0 * 1024;

    f32x4 acc0[8], acc1[8];
    #pragma unroll
    for (int t = 0; t < 8; t++) { acc0[t] = (f32x4){0,0,0,0}; acc1[t] = (f32x4){0,0,0,0}; }

    // prologue: stage kt=0 into buf0
    #pragma unroll
    for (int r = 0; r < 4; r++)
        stage16(gbase + r * 512, lds_c0 + r * 1024);
    __syncthreads();

    for (int kt = 0; kt < 16; kt++) {
        int cur = (kt & 1) << 15;
        bf16x8 a0 = a0p[kt * 4];
        bf16x8 a1 = a1p[kt * 4];
        if (kt < 15) {   // prefetch next slice into other buffer
            const __hip_bfloat16* g = gbase + (size_t)(kt + 1) * 16384;
            char* lb = lds_c0 + (((kt + 1) & 1) << 15);
            #pragma unroll
            for (int r = 0; r < 4; r++)
                stage16(g + r * 512, lb + r * 1024);
        }
        #pragma unroll
        for (int t = 0; t < 8; t++) {
            bf16x8 bf = *(const bf16x8*)(smem + cur + (((wn * 8 + t) * 64 + lane) << 4));
            acc0[t] = __builtin_amdgcn_mfma_f32_16x16x32_bf16(a0, bf, acc0[t], 0, 0, 0);
            acc1[t] = __builtin_amdgcn_mfma_f32_16x16x32_bf16(a1, bf, acc1[t], 0, 0, 0);
        }
        __syncthreads();  // drains vmcnt: next buffer staged; all waves done reading cur
    }

    // epilogue: bias + LN stats
    float bia[8], gam[8], bet[8];
    #pragma unroll
    for (int t = 0; t < 8; t++) {
        int col = wn * 128 + t * 16 + coll;
        bia[t] = bias[col]; gam[t] = gamma[col]; bet[t] = beta[col];
    }
    #pragma unroll
    for (int f = 0; f < 2; f++) {
        f32x4* acc = f ? acc1 : acc0;
        #pragma unroll
        for (int r = 0; r < 4; r++) {
            float s = 0.f, q = 0.f;
            #pragma unroll
            for (int t = 0; t < 8; t++) {
                float v = acc[t][r] + bia[t];
                acc[t][r] = v;
                s += v; q += v * v;
            }
            #pragma unroll
            for (int off = 1; off < 16; off <<= 1) {
                s += __shfl_xor(s, off, 64);
                q += __shfl_xor(q, off, 64);
            }
            if (coll == 0) {
                int rb = wm * 16 + f * 32 + l4 * 4 + r;
                s_sum[rb][wn] = s;
                s_sq[rb][wn] = q;
            }
        }
    }
    __syncthreads();

    #pragma unroll
    for (int f = 0; f < 2; f++) {
        f32x4* acc = f ? acc1 : acc0;
        #pragma unroll
        for (int r = 0; r < 4; r++) {
            int rb = wm * 16 + f * 32 + l4 * 4 + r;
            int gr = bm0 + rb;
            if (gr >= M) continue;
            float s = s_sum[rb][0] + s_sum[rb][1] + s_sum[rb][2] + s_sum[rb][3];
            float q = s_sq[rb][0] + s_sq[rb][1] + s_sq[rb][2] + s_sq[rb][3];
            float mean = s * (1.0f / 512.0f);
            float var = q * (1.0f / 512.0f) - mean * mean;
            float rstd = rsqrtf(fmaxf(var, 0.f) + 1e-5f);
            float* orow = out + (size_t)gr * D + wn * 128 + coll;
            #pragma unroll
            for (int t = 0; t < 8; t++) {
                float y = (acc[t][r] - mean) * rstd * gam[t] + bet[t];
                // tanh-GELU: y * sigmoid(2*0.79788456*(y + 0.044715 y^3)), exp2-folded
                float yy = y * y;
                float pz = fmaf(yy, -0.1029423374f, -2.3022076728f);  // *log2(e), negated
                float e = __builtin_amdgcn_exp2f(y * pz);
                float g = y * __builtin_amdgcn_rcpf(1.0f + e);
                orow[t * 16] = g;
            }
        }
    }
}

extern "C" void kernel_launch(void* const* d_in, const int* in_sizes, int n_in,
                              void* d_out, int out_size, void* d_ws, size_t ws_size,
                              hipStream_t stream) {
    const float* x     = (const float*)d_in[0];
    const float* W     = (const float*)d_in[1];
    const float* b     = (const float*)d_in[2];
    const float* gamma = (const float*)d_in[3];
    const float* beta  = (const float*)d_in[4];
    const int*   src   = (const int*)d_in[5];
    const int*   dst   = (const int*)d_in[6];
    int N = in_sizes[0] / D;
    int E = in_sizes[5];
    float* out = (float*)d_out;

    int* deg_out   = (int*)d_ws;                 // N
    int* deg_in    = deg_out + N;                // N
    int* row_start = deg_in + N;                 // N+1
    int* cursor    = row_start + N + 1;          // N
    int* partials  = cursor + N;                 // <=64
    int* csr_src   = partials + 64;              // E
    uintptr_t p = (uintptr_t)(csr_src + E);
    p = (p + 255) & ~(uintptr_t)255;
    __hip_bfloat16* A = (__hip_bfloat16*)p;      // N*D bf16
    p += (size_t)N * D * sizeof(__hip_bfloat16);
    p = (p + 255) & ~(uintptr_t)255;
    __hip_bfloat16* Wp = (__hip_bfloat16*)p;     // D*D bf16
    p += (size_t)D * D * sizeof(__hip_bfloat16);
    p = (p + 255) & ~(uintptr_t)255;
    __hip_bfloat16* xs = (__hip_bfloat16*)p;     // N*D bf16
    size_t need_xs = (p - (uintptr_t)d_ws) + (size_t)N * D * sizeof(__hip_bfloat16);
    bool use_bf16_gather = (ws_size >= need_xs);

    hipMemsetAsync(deg_out, 0, (size_t)2 * N * sizeof(int), stream);
    hipMemsetAsync(cursor, 0, (size_t)N * sizeof(int), stream);

    k_hist<<<(E + 255) / 256, 256, 0, stream>>>(src, dst, deg_out, deg_in, E);
    int nb1 = (N + 1023) / 1024;
    k_scan1<<<nb1, 1024, 0, stream>>>(deg_in, row_start, partials, N);
    if (nb1 <= 64)
        k_scan2w<<<1, 64, 0, stream>>>(partials, row_start, nb1, N);
    else
        k_scan2s<<<1, 64, 0, stream>>>(partials, row_start, nb1, N);
    k_scan3<<<(N + 255) / 256, 256, 0, stream>>>(row_start, partials, N);
    k_fill<<<(E + 255) / 256, 256, 0, stream>>>(src, dst, row_start, cursor, csr_src, E);

    if (use_bf16_gather) {
        int total16 = N * 64;
        k_scale<<<(total16 + 255) / 256, 256, 0, stream>>>(x, deg_out, xs, total16);
        k_spmm<<<(N + 3) / 4, 256, 0, stream>>>(xs, row_start, csr_src, A, N);
    } else {
        k_spmm_f32<<<(N + 3) / 4, 256, 0, stream>>>(x, row_start, csr_src, deg_out, A, N);
    }
    k_packw<<<512, 64, 0, stream>>>(W, Wp);
    k_gemm<<<(N + 63) / 64, 512, 0, stream>>>(A, Wp, b, gamma, beta, out, N);
}

// Round 4
// 238.273 us; speedup vs baseline: 1.3018x; 1.0370x over previous
//
#include <hip/hip_runtime.h>
#include <hip/hip_bf16.h>

#define D 512

typedef __attribute__((ext_vector_type(8))) short bf16x8;
typedef __attribute__((ext_vector_type(4))) float f32x4;

__device__ inline float b2f(short h) {
    union { unsigned u; float f; } c;
    c.u = ((unsigned)(unsigned short)h) << 16;
    return c.f;
}

__device__ __forceinline__ void stage16(const void* g, void* l) {
    __builtin_amdgcn_global_load_lds((const __attribute__((address_space(1))) void*)g,
                                     (__attribute__((address_space(3))) void*)l, 16, 0, 0);
}

// ---------------- degree histograms ----------------
__global__ void k_hist(const int* __restrict__ src, const int* __restrict__ dst,
                       int* __restrict__ deg_out, int* __restrict__ deg_in, int E) {
    int e = blockIdx.x * 256 + threadIdx.x;
    if (e < E) {
        atomicAdd(&deg_out[src[e]], 1);
        atomicAdd(&deg_in[dst[e]], 1);
    }
}

// ---------------- pre-scale x by rsqrt(deg_out) -> bf16 xs ----------------
__global__ __launch_bounds__(256)
void k_scale(const float* __restrict__ x, const int* __restrict__ deg_out,
             __hip_bfloat16* __restrict__ xs, int total16) {
    int i = blockIdx.x * 256 + threadIdx.x;   // one thread = 8 elements
    if (i >= total16) return;
    int node = i >> 6;
    float w = rsqrtf((float)max(deg_out[node], 1));
    const float4* p = (const float4*)(x + (size_t)i * 8);
    float4 a = p[0], b = p[1];
    union { float4 f4; __hip_bfloat16 h[8]; } o;
    o.h[0] = __float2bfloat16(a.x * w);
    o.h[1] = __float2bfloat16(a.y * w);
    o.h[2] = __float2bfloat16(a.z * w);
    o.h[3] = __float2bfloat16(a.w * w);
    o.h[4] = __float2bfloat16(b.x * w);
    o.h[5] = __float2bfloat16(b.y * w);
    o.h[6] = __float2bfloat16(b.z * w);
    o.h[7] = __float2bfloat16(b.w * w);
    *(float4*)(xs + (size_t)i * 8) = o.f4;
}

// ---------------- exclusive scan of deg_in -> row_start ----------------
__global__ void k_scan1(const int* __restrict__ deg_in, int* __restrict__ row_start,
                        int* __restrict__ partials, int N) {
    __shared__ int sm[1024];
    int tid = threadIdx.x;
    int i = blockIdx.x * 1024 + tid;
    int v = (i < N) ? deg_in[i] : 0;
    sm[tid] = v;
    __syncthreads();
    int acc = v;
    #pragma unroll
    for (int off = 1; off < 1024; off <<= 1) {
        int t = (tid >= off) ? sm[tid - off] : 0;
        __syncthreads();
        acc += t;
        sm[tid] = acc;
        __syncthreads();
    }
    if (i < N) row_start[i] = acc - v;
    if (tid == 1023) partials[blockIdx.x] = acc;
}

__global__ void k_scan2w(int* __restrict__ partials, int* __restrict__ row_start,
                         int nb, int N) {
    int lane = threadIdx.x;
    int orig = (lane < nb) ? partials[lane] : 0;
    int v = orig;
    #pragma unroll
    for (int off = 1; off < 64; off <<= 1) {
        int t = __shfl_up(v, off, 64);
        if (lane >= off) v += t;
    }
    if (lane < nb) partials[lane] = v - orig;
    if (lane == 63) row_start[N] = v;
}

__global__ void k_scan2s(int* __restrict__ partials, int* __restrict__ row_start,
                         int nb, int N) {
    if (threadIdx.x == 0 && blockIdx.x == 0) {
        int run = 0;
        for (int b = 0; b < nb; b++) { int t = partials[b]; partials[b] = run; run += t; }
        row_start[N] = run;
    }
}

__global__ void k_scan3(int* __restrict__ row_start, const int* __restrict__ partials, int N) {
    int i = blockIdx.x * 256 + threadIdx.x;
    if (i < N) row_start[i] += partials[i >> 10];
}

// ---------------- CSR bucket fill ----------------
__global__ void k_fill(const int* __restrict__ src, const int* __restrict__ dst,
                       const int* __restrict__ row_start, int* __restrict__ cursor,
                       int* __restrict__ csr_src, int E) {
    int e = blockIdx.x * 256 + threadIdx.x;
    if (e < E) {
        int d = dst[e];
        int slot = atomicAdd(&cursor[d], 1);
        csr_src[row_start[d] + slot] = src[e];
    }
}

// ---------------- SpMM over bf16 pre-scaled rows ----------------
__global__ __launch_bounds__(256)
void k_spmm(const __hip_bfloat16* __restrict__ xs, const int* __restrict__ row_start,
            const int* __restrict__ csr_src, __hip_bfloat16* __restrict__ A, int N) {
    int wid = threadIdx.x >> 6;
    int lane = threadIdx.x & 63;
    int node = blockIdx.x * 4 + wid;
    if (node >= N) return;
    int rs = row_start[node], re = row_start[node + 1];

    float acc[8];
    #pragma unroll
    for (int k = 0; k < 8; k++) acc[k] = 0.f;
    const __hip_bfloat16* xl = xs + (size_t)lane * 8;

    int j = rs;
    for (; j + 4 <= re; j += 4) {
        int s0 = csr_src[j], s1 = csr_src[j + 1], s2 = csr_src[j + 2], s3 = csr_src[j + 3];
        bf16x8 v0 = *(const bf16x8*)(xl + (size_t)s0 * D);
        bf16x8 v1 = *(const bf16x8*)(xl + (size_t)s1 * D);
        bf16x8 v2 = *(const bf16x8*)(xl + (size_t)s2 * D);
        bf16x8 v3 = *(const bf16x8*)(xl + (size_t)s3 * D);
        #pragma unroll
        for (int k = 0; k < 8; k++)
            acc[k] += (b2f(v0[k]) + b2f(v1[k])) + (b2f(v2[k]) + b2f(v3[k]));
    }
    for (; j < re; j++) {
        int s = csr_src[j];
        bf16x8 v = *(const bf16x8*)(xl + (size_t)s * D);
        #pragma unroll
        for (int k = 0; k < 8; k++) acc[k] += b2f(v[k]);
    }

    float rn = rsqrtf((float)max(re - rs, 1));
    union { float4 f4; __hip_bfloat16 h[8]; } o;
    #pragma unroll
    for (int k = 0; k < 8; k++) o.h[k] = __float2bfloat16(acc[k] * rn);
    *(float4*)(A + (size_t)node * D + lane * 8) = o.f4;
}

// ---------------- f32 fallback SpMM ----------------
__global__ __launch_bounds__(256)
void k_spmm_f32(const float* __restrict__ x, const int* __restrict__ row_start,
                const int* __restrict__ csr_src, const int* __restrict__ deg_out,
                __hip_bfloat16* __restrict__ A, int N) {
    int wid = threadIdx.x >> 6;
    int lane = threadIdx.x & 63;
    int node = blockIdx.x * 4 + wid;
    if (node >= N) return;
    int rs = row_start[node], re = row_start[node + 1];
    float4 acc0 = {0.f, 0.f, 0.f, 0.f};
    float4 acc1 = {0.f, 0.f, 0.f, 0.f};
    const float* xl = x + (size_t)lane * 8;
    for (int j = rs; j < re; j++) {
        int s = csr_src[j];
        float w = rsqrtf((float)max(deg_out[s], 1));
        const float4* p = (const float4*)(xl + (size_t)s * D);
        float4 a = p[0], b = p[1];
        acc0.x += a.x * w; acc0.y += a.y * w; acc0.z += a.z * w; acc0.w += a.w * w;
        acc1.x += b.x * w; acc1.y += b.y * w; acc1.z += b.z * w; acc1.w += b.w * w;
    }
    float rn = rsqrtf((float)max(re - rs, 1));
    union { float4 f4; __hip_bfloat16 h[8]; } o;
    o.h[0] = __float2bfloat16(acc0.x * rn);
    o.h[1] = __float2bfloat16(acc0.y * rn);
    o.h[2] = __float2bfloat16(acc0.z * rn);
    o.h[3] = __float2bfloat16(acc0.w * rn);
    o.h[4] = __float2bfloat16(acc1.x * rn);
    o.h[5] = __float2bfloat16(acc1.y * rn);
    o.h[6] = __float2bfloat16(acc1.z * rn);
    o.h[7] = __float2bfloat16(acc1.w * rn);
    *(float4*)(A + (size_t)node * D + lane * 8) = o.f4;
}

// ---------------- pack W into MFMA B-fragment layout ----------------
// tile = kt*32 + nt; element (tile, lane, j) = W[kt*32 + (lane>>4)*8 + j][nt*16 + (lane&15)]
// => per-kt slice (32 tiles) is a contiguous 32KB block for global_load_lds.
__global__ void k_packw(const float* __restrict__ W, __hip_bfloat16* __restrict__ Wp) {
    int tile = blockIdx.x;        // 0..511
    int lane = threadIdx.x;       // 0..63
    int kt = tile >> 5, nt = tile & 31;
    int k0 = kt * 32 + (lane >> 4) * 8;
    int n  = nt * 16 + (lane & 15);
    union { float4 f4; __hip_bfloat16 h[8]; } o;
    #pragma unroll
    for (int j = 0; j < 8; j++)
        o.h[j] = __float2bfloat16(W[(size_t)(k0 + j) * D + n]);
    *(float4*)(Wp + ((size_t)tile * 64 + lane) * 8) = o.f4;
}

// ---------------- fused GEMM + bias + LayerNorm + tanh-GELU ----------------
// 512 thr = 8 waves (wm = wid>>2 in 0..1, wn = wid&3); block = 64 rows x 512 cols.
// Per wave: 2 M-frags (rows wm*16+coll, +32), 8 N-tiles, K-loop 16 x 32.
// BOTH Wp (32KB/kt) and A-tile (4KB/kt) staged via global_load_lds, double-buffered,
// prefetch depth 2, counted vmcnt + raw s_barrier (never drain to 0 in steady state).
// A LDS layout: [j=0..3][row=0..63] x 16B -> frag read l4*1024 + row*16, conflict-free.
__global__ __launch_bounds__(512, 4)
void k_gemm(const __hip_bfloat16* __restrict__ A, const __hip_bfloat16* __restrict__ Wp,
            const float* __restrict__ bias, const float* __restrict__ gamma,
            const float* __restrict__ beta, float* __restrict__ out, int M) {
    __shared__ __align__(16) char smem[2 * 32768 + 2 * 4096];  // W buf0|buf1, A buf0|buf1
    __shared__ float s_sum[64][4];
    __shared__ float s_sq[64][4];
    char* smemA = smem + 65536;

    int tid = threadIdx.x;
    int wid = tid >> 6, lane = tid & 63;
    int wm = wid >> 2;
    int wn = wid & 3;
    int l4 = lane >> 4, coll = lane & 15;
    int bm0 = blockIdx.x * 64;

    int r0 = wm * 16 + coll;      // A-tile-local row of frag0 (0..31)
    int r1 = r0 + 32;             // frag1 (32..63)

    // staging geometry: Wp chunk c = wid*4 + r covers bytes [c*1024, c*1024+1024) of slice
    int c0 = wid * 4;
    const char* gw_base = (const char*)Wp + (size_t)c0 * 1024 + (size_t)lane * 16; // +kt*32768, +r*1024
    // A stage: wave w (<4) stages j=w sub-column for all 64 rows
    int ga_row = bm0 + lane;
    if (ga_row > M - 1) ga_row = M - 1;                 // clamp; dup rows never stored
    const char* ga_base = (const char*)A + (size_t)ga_row * 1024 + (size_t)wid * 16; // +kt*64

    f32x4 acc0[8], acc1[8];
    #pragma unroll
    for (int t = 0; t < 8; t++) { acc0[t] = (f32x4){0,0,0,0}; acc1[t] = (f32x4){0,0,0,0}; }

    auto STAGE = [&](int kt, int buf) {
        const char* gw = gw_base + (size_t)kt * 32768;
        char* lw = smem + buf * 32768 + c0 * 1024;
        #pragma unroll
        for (int r = 0; r < 4; r++)
            stage16(gw + r * 1024, lw + r * 1024);
        if (wid < 4)
            stage16(ga_base + (size_t)kt * 64, smemA + buf * 4096 + wid * 1024);
    };

    // prologue: two tiles in flight, wait for tile 0 only
    STAGE(0, 0);
    STAGE(1, 1);
    asm volatile("s_waitcnt vmcnt(4)" ::: "memory");
    __builtin_amdgcn_sched_barrier(0);
    __builtin_amdgcn_s_barrier();

    for (int kt = 0; kt < 14; kt++) {
        int cur = kt & 1;
        char* aw = smemA + cur * 4096 + l4 * 1024;
        bf16x8 a0 = *(const bf16x8*)(aw + r0 * 16);
        bf16x8 a1 = *(const bf16x8*)(aw + r1 * 16);
        bf16x8 bf[8];
        char* ww = smem + cur * 32768 + (size_t)wn * 8192 + lane * 16;
        #pragma unroll
        for (int t = 0; t < 8; t++)
            bf[t] = *(const bf16x8*)(ww + t * 1024);
        asm volatile("s_waitcnt lgkmcnt(0)" ::: "memory");  // frags in regs
        __builtin_amdgcn_sched_barrier(0);
        __builtin_amdgcn_s_barrier();                       // all waves done reading buf[cur]
        STAGE(kt + 2, cur);                                 // overwrite it with tile kt+2
        #pragma unroll
        for (int t = 0; t < 8; t++) {
            acc0[t] = __builtin_amdgcn_mfma_f32_16x16x32_bf16(a0, bf[t], acc0[t], 0, 0, 0);
            acc1[t] = __builtin_amdgcn_mfma_f32_16x16x32_bf16(a1, bf[t], acc1[t], 0, 0, 0);
        }
        asm volatile("s_waitcnt vmcnt(4)" ::: "memory");    // tile kt+1 staged; kt+2 in flight
        __builtin_amdgcn_sched_barrier(0);
        __builtin_amdgcn_s_barrier();
    }
    // kt = 14 (no more staging; drain fully so tile 15 is readable)
    {
        char* aw = smemA + 0 * 4096 + l4 * 1024;
        bf16x8 a0 = *(const bf16x8*)(aw + r0 * 16);
        bf16x8 a1 = *(const bf16x8*)(aw + r1 * 16);
        char* ww = smem + 0 * 32768 + (size_t)wn * 8192 + lane * 16;
        #pragma unroll
        for (int t = 0; t < 8; t++) {
            bf16x8 bf = *(const bf16x8*)(ww + t * 1024);
            acc0[t] = __builtin_amdgcn_mfma_f32_16x16x32_bf16(a0, bf, acc0[t], 0, 0, 0);
            acc1[t] = __builtin_amdgcn_mfma_f32_16x16x32_bf16(a1, bf, acc1[t], 0, 0, 0);
        }
        asm volatile("s_waitcnt vmcnt(0)" ::: "memory");
        __builtin_amdgcn_sched_barrier(0);
        __builtin_amdgcn_s_barrier();
    }
    // kt = 15
    {
        char* aw = smemA + 1 * 4096 + l4 * 1024;
        bf16x8 a0 = *(const bf16x8*)(aw + r0 * 16);
        bf16x8 a1 = *(const bf16x8*)(aw + r1 * 16);
        char* ww = smem + 1 * 32768 + (size_t)wn * 8192 + lane * 16;
        #pragma unroll
        for (int t = 0; t < 8; t++) {
            bf16x8 bf = *(const bf16x8*)(ww + t * 1024);
            acc0[t] = __builtin_amdgcn_mfma_f32_16x16x32_bf16(a0, bf, acc0[t], 0, 0, 0);
            acc1[t] = __builtin_amdgcn_mfma_f32_16x16x32_bf16(a1, bf, acc1[t], 0, 0, 0);
        }
    }

    // epilogue: bias + LN stats
    float bia[8], gam[8], bet[8];
    #pragma unroll
    for (int t = 0; t < 8; t++) {
        int col = wn * 128 + t * 16 + coll;
        bia[t] = bias[col]; gam[t] = gamma[col]; bet[t] = beta[col];
    }
    #pragma unroll
    for (int f = 0; f < 2; f++) {
        f32x4* acc = f ? acc1 : acc0;
        #pragma unroll
        for (int r = 0; r < 4; r++) {
            float s = 0.f, q = 0.f;
            #pragma unroll
            for (int t = 0; t < 8; t++) {
                float v = acc[t][r] + bia[t];
                acc[t][r] = v;
                s += v; q += v * v;
            }
            #pragma unroll
            for (int off = 1; off < 16; off <<= 1) {
                s += __shfl_xor(s, off, 64);
                q += __shfl_xor(q, off, 64);
            }
            if (coll == 0) {
                int rb = wm * 16 + f * 32 + l4 * 4 + r;
                s_sum[rb][wn] = s;
                s_sq[rb][wn] = q;
            }
        }
    }
    __syncthreads();

    #pragma unroll
    for (int f = 0; f < 2; f++) {
        f32x4* acc = f ? acc1 : acc0;
        #pragma unroll
        for (int r = 0; r < 4; r++) {
            int rb = wm * 16 + f * 32 + l4 * 4 + r;
            int gr = bm0 + rb;
            if (gr >= M) continue;
            float s = s_sum[rb][0] + s_sum[rb][1] + s_sum[rb][2] + s_sum[rb][3];
            float q = s_sq[rb][0] + s_sq[rb][1] + s_sq[rb][2] + s_sq[rb][3];
            float mean = s * (1.0f / 512.0f);
            float var = q * (1.0f / 512.0f) - mean * mean;
            float rstd = rsqrtf(fmaxf(var, 0.f) + 1e-5f);
            float* orow = out + (size_t)gr * D + wn * 128 + coll;
            #pragma unroll
            for (int t = 0; t < 8; t++) {
                float y = (acc[t][r] - mean) * rstd * gam[t] + bet[t];
                // tanh-GELU: y * sigmoid(1.5957692*(y + 0.044715 y^3)), exp2-folded
                float yy = y * y;
                float pz = fmaf(yy, -0.1029423374f, -2.3022076728f);
                float e = __builtin_amdgcn_exp2f(y * pz);
                float g = y * __builtin_amdgcn_rcpf(1.0f + e);
                orow[t * 16] = g;
            }
        }
    }
}

extern "C" void kernel_launch(void* const* d_in, const int* in_sizes, int n_in,
                              void* d_out, int out_size, void* d_ws, size_t ws_size,
                              hipStream_t stream) {
    const float* x     = (const float*)d_in[0];
    const float* W     = (const float*)d_in[1];
    const float* b     = (const float*)d_in[2];
    const float* gamma = (const float*)d_in[3];
    const float* beta  = (const float*)d_in[4];
    const int*   src   = (const int*)d_in[5];
    const int*   dst   = (const int*)d_in[6];
    int N = in_sizes[0] / D;
    int E = in_sizes[5];
    float* out = (float*)d_out;

    int* deg_out   = (int*)d_ws;                 // N
    int* deg_in    = deg_out + N;                // N
    int* row_start = deg_in + N;                 // N+1
    int* cursor    = row_start + N + 1;          // N
    int* partials  = cursor + N;                 // <=64
    int* csr_src   = partials + 64;              // E
    uintptr_t p = (uintptr_t)(csr_src + E);
    p = (p + 255) & ~(uintptr_t)255;
    __hip_bfloat16* A = (__hip_bfloat16*)p;      // N*D bf16
    p += (size_t)N * D * sizeof(__hip_bfloat16);
    p = (p + 255) & ~(uintptr_t)255;
    __hip_bfloat16* Wp = (__hip_bfloat16*)p;     // D*D bf16
    p += (size_t)D * D * sizeof(__hip_bfloat16);
    p = (p + 255) & ~(uintptr_t)255;
    __hip_bfloat16* xs = (__hip_bfloat16*)p;     // N*D bf16
    size_t need_xs = (p - (uintptr_t)d_ws) + (size_t)N * D * sizeof(__hip_bfloat16);
    bool use_bf16_gather = (ws_size >= need_xs);

    hipMemsetAsync(deg_out, 0, (size_t)2 * N * sizeof(int), stream);
    hipMemsetAsync(cursor, 0, (size_t)N * sizeof(int), stream);

    k_hist<<<(E + 255) / 256, 256, 0, stream>>>(src, dst, deg_out, deg_in, E);
    int nb1 = (N + 1023) / 1024;
    k_scan1<<<nb1, 1024, 0, stream>>>(deg_in, row_start, partials, N);
    if (nb1 <= 64)
        k_scan2w<<<1, 64, 0, stream>>>(partials, row_start, nb1, N);
    else
        k_scan2s<<<1, 64, 0, stream>>>(partials, row_start, nb1, N);
    k_scan3<<<(N + 255) / 256, 256, 0, stream>>>(row_start, partials, N);
    k_fill<<<(E + 255) / 256, 256, 0, stream>>>(src, dst, row_start, cursor, csr_src, E);

    if (use_bf16_gather) {
        int total16 = N * 64;
        k_scale<<<(total16 + 255) / 256, 256, 0, stream>>>(x, deg_out, xs, total16);
        k_spmm<<<(N + 3) / 4, 256, 0, stream>>>(xs, row_start, csr_src, A, N);
    } else {
        k_spmm_f32<<<(N + 3) / 4, 256, 0, stream>>>(x, row_start, csr_src, deg_out, A, N);
    }
    k_packw<<<512, 64, 0, stream>>>(W, Wp);
    k_gemm<<<(N + 63) / 64, 512, 0, stream>>>(A, Wp, b, gamma, beta, out, N);
}